// Round 1
// baseline (185.915 us; speedup 1.0000x reference)
//
#include <hip/hip_runtime.h>
#include <hip/hip_bf16.h>
#include <cstdint>
#include <cstddef>

#define NROWS 8192
#define KDIM  2048
#define ODIM  1000
#define NSUB  8
#define OPAD  1024   // padded output dim for Wt (8 tiles of 128)

typedef __attribute__((ext_vector_type(4))) float f32x4;
typedef __attribute__((ext_vector_type(8))) short short8v;
typedef __attribute__((ext_vector_type(4))) unsigned short u16x4;

__device__ __forceinline__ unsigned short f2bf(float f){
  unsigned u = __builtin_bit_cast(unsigned, f);
  unsigned r = (u + 0x7FFFu + ((u >> 16) & 1u)) >> 16;  // RNE
  return (unsigned short)r;
}

__device__ __forceinline__ void gload16(const void* g, void* l){
  // async global->LDS, 16B per lane; LDS dest = wave-uniform base + lane*16
  __builtin_amdgcn_global_load_lds(
      (const __attribute__((address_space(1))) void*)g,
      (__attribute__((address_space(3))) void*)l, 16, 0, 0);
}

// ---------------- K1a: per-subject histogram + rank ----------------
__global__ void hist_kernel(const int* __restrict__ sid, int* counts, int* myrank){
  int i = blockIdx.x * 256 + threadIdx.x;
  if (i < NROWS){
    int s = sid[i];
    myrank[i] = atomicAdd(&counts[s], 1);
  }
}

// ---------------- K1b: exclusive scan of 8 counts ----------------
__global__ void scan_kernel(const int* __restrict__ counts, int* offsets){
  if (threadIdx.x == 0 && blockIdx.x == 0){
    int a = 0;
    for (int i = 0; i < NSUB; i++){ offsets[i] = a; a += counts[i]; }
  }
}

// ---------------- K1c: scatter row indices into sorted order ----------------
__global__ void scatter_kernel(const int* __restrict__ sid, const int* __restrict__ offsets,
                               const int* __restrict__ myrank, int* __restrict__ perm){
  int i = blockIdx.x * 256 + threadIdx.x;
  if (i < NROWS){
    perm[offsets[sid[i]] + myrank[i]] = i;
  }
}

// ---------------- K2: gather rows via perm and convert fp32 -> bf16 ----------------
__global__ __launch_bounds__(256) void gather_cvt(const float* __restrict__ x,
                                                  const int* __restrict__ perm,
                                                  unsigned short* __restrict__ xs){
  int p = blockIdx.x;                 // sorted position 0..8191
  int orow = perm[p];
  const f32x4* src = (const f32x4*)(x + (size_t)orow * KDIM);
  u16x4* dst = (u16x4*)(xs + (size_t)p * KDIM);
  int t = threadIdx.x;
  #pragma unroll
  for (int c = 0; c < 2; c++){
    f32x4 v = src[c * 256 + t];
    u16x4 o;
    o[0] = f2bf(v[0]); o[1] = f2bf(v[1]); o[2] = f2bf(v[2]); o[3] = f2bf(v[3]);
    dst[c * 256 + t] = o;
  }
}

// ---------------- K3: transpose + convert W[s][k][o] -> Wt[s][o][k] bf16 ----------------
__global__ __launch_bounds__(256) void transpose_cvt(const float* __restrict__ W,
                                                     unsigned short* __restrict__ Wt){
  __shared__ float tile[64][65];      // +1 pad breaks bank conflicts
  int s  = blockIdx.z;
  int kt = blockIdx.y;                // 0..31
  int ot = blockIdx.x;                // 0..15
  int k0 = kt * 64, o0 = ot * 64;
  int t = threadIdx.x;
  int ol = t & 63, kr = t >> 6;       // 4 k-rows in parallel
  const float* src = W + ((size_t)s * KDIM + k0) * ODIM + o0;
  bool oval = (o0 + ol) < ODIM;
  #pragma unroll
  for (int it = 0; it < 16; it++){
    int k = kr * 16 + it;
    tile[k][ol] = oval ? src[(size_t)k * ODIM + ol] : 0.f;
  }
  __syncthreads();
  int kp = t & 31, orow = t >> 5;     // write 2 bf16 (4B) per iter, coalesced in kp
  unsigned short* dst = Wt + ((size_t)(s * OPAD + o0)) * KDIM + k0;
  #pragma unroll
  for (int it = 0; it < 8; it++){
    int o = orow + it * 8;
    if (o0 + o < ODIM){
      unsigned lo = f2bf(tile[kp * 2][o]);
      unsigned hi = f2bf(tile[kp * 2 + 1][o]);
      *(unsigned*)(dst + (size_t)o * KDIM + kp * 2) = lo | (hi << 16);
    }
  }
}

// ---------------- K4: grouped bf16 MFMA GEMM, 128x128 tile, BK=64 ----------------
__global__ __launch_bounds__(256) void gemm_bf16(
    const unsigned short* __restrict__ xs,   // [8192][2048] bf16 (sorted rows)
    const unsigned short* __restrict__ Wt,   // [8][1024][2048] bf16
    const int* __restrict__ counts,
    const int* __restrict__ offsets,
    const int* __restrict__ perm,
    const float* __restrict__ bias,          // [8][1000]
    float* __restrict__ out)                 // [8192][1000]
{
  int s  = blockIdx.z;
  int mt = blockIdx.y;
  int nt = blockIdx.x;
  int cnt = counts[s];
  int loc0 = mt << 7;
  if (loc0 >= cnt) return;                   // inactive m-slot for this subject
  int row0 = offsets[s] + loc0;              // base sorted-row
  int cnt_loc = cnt - loc0;                  // valid rows in tile (may be <128)

  __shared__ unsigned short lA[128 * 64];    // [row][k] bf16, chunk-swizzled
  __shared__ unsigned short lB[128 * 64];    // [o][k]   bf16, chunk-swizzled
  __shared__ int permL[128];

  int t = threadIdx.x;
  int lane = t & 63;
  int wave = t >> 6;

  if (t < 128)
    permL[t] = (t < cnt_loc) ? perm[row0 + t] : -1;

  int wm = (wave >> 1) << 6;                 // wave tile 64x64, 2x2 waves
  int wn = (wave & 1) << 6;

  f32x4 acc[4][4];
  #pragma unroll
  for (int i = 0; i < 4; i++)
    #pragma unroll
    for (int j = 0; j < 4; j++)
      #pragma unroll
      for (int e = 0; e < 4; e++) acc[i][j][e] = 0.f;

  // staging: chunk c = (it*4+wave)*64 + lane; row = c>>3, phys k-chunk = lane&7.
  // source holds logical chunk (kc ^ (row&7)) -> read at phys (j ^ (row&7)). (rule #21)
  int srck = (((lane & 7) ^ ((lane >> 3) & 7)) << 3);  // element offset in 64-k tile
  size_t gAoff[4], gBoff[4];
  unsigned ldsoff[4];
  #pragma unroll
  for (int it = 0; it < 4; it++){
    int cb  = it * 4 + wave;
    int row = (cb << 3) + (lane >> 3);
    int ra  = row0 + row; if (ra > NROWS - 1) ra = NROWS - 1;   // clamp tail
    gAoff[it] = (size_t)ra * KDIM + srck;
    gBoff[it] = ((size_t)(s * OPAD + (nt << 7) + row)) * KDIM + srck;
    ldsoff[it] = (unsigned)(cb << 9);        // *512 elements (64 chunks * 8)
  }

  int frow = lane & 15, fk = lane >> 4;
  int axor = frow & 7;

  for (int k0 = 0; k0 < KDIM; k0 += 64){
    __syncthreads();                         // previous tile consumed
    #pragma unroll
    for (int it = 0; it < 4; it++){
      gload16(xs + gAoff[it] + k0, (void*)(lA + ldsoff[it] + (lane << 3)));
      gload16(Wt + gBoff[it] + k0, (void*)(lB + ldsoff[it] + (lane << 3)));
    }
    __syncthreads();                         // staging complete (vmcnt drained)
    #pragma unroll
    for (int ks = 0; ks < 2; ks++){
      short8v a[4], b[4];
      #pragma unroll
      for (int mi = 0; mi < 4; mi++){
        int row = wm + (mi << 4) + frow;
        int j = (ks << 2) + fk;
        a[mi] = *(const short8v*)&lA[(row << 6) + ((j ^ axor) << 3)];
      }
      #pragma unroll
      for (int ni = 0; ni < 4; ni++){
        int row = wn + (ni << 4) + frow;
        int j = (ks << 2) + fk;
        b[ni] = *(const short8v*)&lB[(row << 6) + ((j ^ axor) << 3)];
      }
      #pragma unroll
      for (int mi = 0; mi < 4; mi++)
        #pragma unroll
        for (int ni = 0; ni < 4; ni++)
          acc[mi][ni] = __builtin_amdgcn_mfma_f32_16x16x32_bf16(a[mi], b[ni], acc[mi][ni], 0, 0, 0);
    }
  }

  // epilogue: C/D layout col=lane&15, row=(lane>>4)*4+reg  [m89/m91 verified]
  float bvn[4]; int ocol[4];
  #pragma unroll
  for (int ni = 0; ni < 4; ni++){
    int o = (nt << 7) + wn + (ni << 4) + frow;
    ocol[ni] = o;
    bvn[ni] = (o < ODIM) ? bias[s * ODIM + o] : 0.f;
  }
  #pragma unroll
  for (int mi = 0; mi < 4; mi++){
    int rbase = wm + (mi << 4) + (fk << 2);
    #pragma unroll
    for (int jj = 0; jj < 4; jj++){
      int orow = permL[rbase + jj];
      if (orow >= 0){
        #pragma unroll
        for (int ni = 0; ni < 4; ni++){
          if (ocol[ni] < ODIM)
            out[(size_t)orow * ODIM + ocol[ni]] = acc[mi][ni][jj] + bvn[ni];
        }
      }
    }
  }
}

// ---------------- fallback: naive fp32 (only if ws too small) ----------------
__global__ __launch_bounds__(256) void naive_kernel(const float* __restrict__ x,
                                                    const int* __restrict__ sid,
                                                    const float* __restrict__ W,
                                                    const float* __restrict__ bias,
                                                    float* __restrict__ out){
  __shared__ float xr[KDIM];
  int row = blockIdx.x;
  int s = sid[row];
  for (int i = threadIdx.x; i < KDIM; i += 256) xr[i] = x[(size_t)row * KDIM + i];
  __syncthreads();
  int o = blockIdx.y * 256 + threadIdx.x;
  if (o >= ODIM) return;
  const float* w = W + (size_t)s * KDIM * ODIM + o;
  float acc = bias[s * ODIM + o];
  for (int k = 0; k < KDIM; k++) acc = fmaf(xr[k], w[(size_t)k * ODIM], acc);
  out[(size_t)row * ODIM + o] = acc;
}

extern "C" void kernel_launch(void* const* d_in, const int* in_sizes, int n_in,
                              void* d_out, int out_size, void* d_ws, size_t ws_size,
                              hipStream_t stream) {
  const float* x    = (const float*)d_in[0];
  const int*   sid  = (const int*)d_in[1];
  const float* W    = (const float*)d_in[2];
  const float* bias = (const float*)d_in[3];
  float* out = (float*)d_out;

  // ws layout
  const size_t XS_BYTES = (size_t)NROWS * KDIM * 2;           // 33.55 MB
  const size_t WT_BYTES = (size_t)NSUB * OPAD * KDIM * 2;     // 33.55 MB
  const size_t need = 64 + 2 * (size_t)NROWS * 4 + XS_BYTES + WT_BYTES;

  if (ws_size < need){
    naive_kernel<<<dim3(NROWS, 4), 256, 0, stream>>>(x, sid, W, bias, out);
    return;
  }

  char* w = (char*)d_ws;
  int* counts  = (int*)w;                      // 8 ints
  int* offsets = counts + 8;                   // 8 ints
  int* myrank  = (int*)(w + 64);               // 8192 ints
  int* perm    = myrank + NROWS;               // 8192 ints
  unsigned short* xs = (unsigned short*)(w + 64 + 2 * (size_t)NROWS * 4);
  unsigned short* Wt = xs + (size_t)NROWS * KDIM;

  hipMemsetAsync(counts, 0, 32, stream);
  hist_kernel   <<<NROWS / 256, 256, 0, stream>>>(sid, counts, myrank);
  scan_kernel   <<<1, 64, 0, stream>>>(counts, offsets);
  scatter_kernel<<<NROWS / 256, 256, 0, stream>>>(sid, offsets, myrank, perm);
  gather_cvt    <<<NROWS, 256, 0, stream>>>(x, perm, xs);
  transpose_cvt <<<dim3(16, 32, NSUB), 256, 0, stream>>>(W, Wt);
  gemm_bf16     <<<dim3(8, 64, NSUB), 256, 0, stream>>>(xs, Wt, counts, offsets, perm, bias, out);
}

// Round 2
// 153.907 us; speedup vs baseline: 1.2080x; 1.2080x over previous
//
#include <hip/hip_runtime.h>
#include <hip/hip_bf16.h>
#include <cstdint>
#include <cstddef>

#define NROWS 8192
#define KDIM  2048
#define ODIM  1000
#define NSUB  8
#define OPAD  1024   // padded output dim for Wt

#define BM 128
#define BN 64
#define BK 64

typedef __attribute__((ext_vector_type(4))) float f32x4;
typedef __attribute__((ext_vector_type(8))) short short8v;
typedef __attribute__((ext_vector_type(4))) unsigned short u16x4;

__device__ __forceinline__ unsigned short f2bf(float f){
  unsigned u = __builtin_bit_cast(unsigned, f);
  unsigned r = (u + 0x7FFFu + ((u >> 16) & 1u)) >> 16;  // RNE
  return (unsigned short)r;
}

__device__ __forceinline__ void gload16(const void* g, void* l){
  __builtin_amdgcn_global_load_lds(
      (const __attribute__((address_space(1))) void*)g,
      (__attribute__((address_space(3))) void*)l, 16, 0, 0);
}

// ---------------- K1: build perm/counts/offsets in ONE kernel ----------------
// block s: stable-compacts indices with sid==s into perm[offsets[s]..].
__global__ __launch_bounds__(256) void build_perm(const int* __restrict__ sid,
                                                  int* __restrict__ counts,
                                                  int* __restrict__ offsets,
                                                  int* __restrict__ perm){
  int s = blockIdx.x;
  __shared__ int shs[NROWS];          // 32KB: cached sid
  __shared__ int red_lt[4], red_eq[4], wsum[4];
  __shared__ int sh_base;

  int t = threadIdx.x, lane = t & 63, wv = t >> 6;

  // pass 1: cache sid, count (v<s) and (v==s)
  int c_lt = 0, c_eq = 0;
  for (int i = t; i < NROWS; i += 256){
    int v = sid[i];
    shs[i] = v;
    c_lt += (v < s);
    c_eq += (v == s);
  }
  #pragma unroll
  for (int d = 32; d >= 1; d >>= 1){
    c_lt += __shfl_xor(c_lt, d);
    c_eq += __shfl_xor(c_eq, d);
  }
  if (lane == 0){ red_lt[wv] = c_lt; red_eq[wv] = c_eq; }
  __syncthreads();
  if (t == 0){
    int lt = red_lt[0] + red_lt[1] + red_lt[2] + red_lt[3];
    int eq = red_eq[0] + red_eq[1] + red_eq[2] + red_eq[3];
    offsets[s] = lt;
    counts[s]  = eq;
    sh_base = lt;
  }
  __syncthreads();
  int base = sh_base;

  // pass 2: stable compaction
  for (int c0 = 0; c0 < NROWS; c0 += 256){
    int v = shs[c0 + t];
    bool eq = (v == s);
    unsigned long long m = __ballot(eq);
    int rk = __popcll(m & ((1ull << lane) - 1ull));
    int wc = __popcll(m);
    if (lane == 0) wsum[wv] = wc;
    __syncthreads();
    int woff = 0;
    #pragma unroll
    for (int w = 0; w < 4; w++) if (w < wv) woff += wsum[w];
    int tot = wsum[0] + wsum[1] + wsum[2] + wsum[3];
    if (eq) perm[base + woff + rk] = c0 + t;
    base += tot;
    __syncthreads();
  }
}

// ---------------- K2: gather rows via perm, fp32 -> bf16 ----------------
__global__ __launch_bounds__(256) void gather_cvt(const float* __restrict__ x,
                                                  const int* __restrict__ perm,
                                                  unsigned short* __restrict__ xs){
  int p = blockIdx.x;
  int orow = perm[p];
  const f32x4* src = (const f32x4*)(x + (size_t)orow * KDIM);
  u16x4* dst = (u16x4*)(xs + (size_t)p * KDIM);
  int t = threadIdx.x;
  #pragma unroll
  for (int c = 0; c < 2; c++){
    f32x4 v = src[c * 256 + t];
    u16x4 o;
    o[0] = f2bf(v[0]); o[1] = f2bf(v[1]); o[2] = f2bf(v[2]); o[3] = f2bf(v[3]);
    dst[c * 256 + t] = o;
  }
}

// ---------------- K3: transpose + cvt W[s][k][o] -> Wt[s][o][k] bf16 ----------------
__global__ __launch_bounds__(256) void transpose_cvt(const float* __restrict__ W,
                                                     unsigned short* __restrict__ Wt){
  __shared__ float tile[64][65];
  int s  = blockIdx.z;
  int kt = blockIdx.y;                // 0..31
  int ot = blockIdx.x;                // 0..15
  int k0 = kt * 64, o0 = ot * 64;
  int t = threadIdx.x;
  int ol = t & 63, kr = t >> 6;
  const float* src = W + ((size_t)s * KDIM + k0) * ODIM + o0;
  bool oval = (o0 + ol) < ODIM;
  #pragma unroll
  for (int it = 0; it < 16; it++){
    int k = kr * 16 + it;
    tile[k][ol] = oval ? src[(size_t)k * ODIM + ol] : 0.f;
  }
  __syncthreads();
  int kp = t & 31, orow = t >> 5;
  unsigned short* dst = Wt + ((size_t)(s * OPAD + o0)) * KDIM + k0;
  #pragma unroll
  for (int it = 0; it < 8; it++){
    int o = orow + it * 8;
    bool valid = (o0 + o) < ODIM;        // pad rows [1000,1024) -> zeros
    unsigned lo = valid ? (unsigned)f2bf(tile[kp * 2][o])     : 0u;
    unsigned hi = valid ? (unsigned)f2bf(tile[kp * 2 + 1][o]) : 0u;
    *(unsigned*)(dst + (size_t)o * KDIM + kp * 2) = lo | (hi << 16);
  }
}

// ---------------- K4: grouped bf16 MFMA GEMM, 128x64 tile, BK=64, 2-phase dbuf ----------------
__global__ __launch_bounds__(256) void gemm_bf16(
    const unsigned short* __restrict__ xs,   // [8192][2048] bf16 (sorted)
    const unsigned short* __restrict__ Wt,   // [8][1024][2048] bf16
    const int* __restrict__ counts,
    const int* __restrict__ offsets,
    const int* __restrict__ perm,
    const float* __restrict__ bias,          // [8][1000]
    float* __restrict__ out)                 // [8192][1000]
{
  int s  = blockIdx.z;
  int mt = blockIdx.y;
  int nt = blockIdx.x;
  int cnt = counts[s];
  int loc0 = mt * BM;
  if (loc0 >= cnt) return;
  int row0 = offsets[s] + loc0;
  int cnt_loc = cnt - loc0;

  __shared__ unsigned short lA[2][BM * BK];  // 2 x 16KB
  __shared__ unsigned short lB[2][BN * BK];  // 2 x 8KB
  __shared__ int permL[BM];

  int t = threadIdx.x;
  int lane = t & 63;
  int wave = t >> 6;

  if (t < BM)
    permL[t] = (t < cnt_loc) ? perm[row0 + t] : -1;

  int wm = (wave >> 1) << 6;   // 2x2 waves over 128x64; wave tile 64x32
  int wn = (wave & 1) << 5;

  f32x4 acc[4][2];
  #pragma unroll
  for (int i = 0; i < 4; i++)
    #pragma unroll
    for (int j = 0; j < 2; j++)
      #pragma unroll
      for (int e = 0; e < 4; e++) acc[i][j][e] = 0.f;

  // staging: chunk-swizzled source (rule #21): phys chunk lane&7 holds logical (lane&7)^(row&7)
  int srck = (((lane & 7) ^ ((lane >> 3) & 7)) << 3);
  size_t gAoff[4]; unsigned lAoff[4];
  #pragma unroll
  for (int it = 0; it < 4; it++){
    int cb  = it * 4 + wave;               // 0..15
    int row = (cb << 3) + (lane >> 3);     // 0..127
    int ra  = row0 + row; if (ra > NROWS - 1) ra = NROWS - 1;
    gAoff[it] = (size_t)ra * KDIM + srck;
    lAoff[it] = (unsigned)((cb << 9) + (lane << 3));
  }
  size_t gBoff[2]; unsigned lBoff[2];
  #pragma unroll
  for (int it = 0; it < 2; it++){
    int cb  = it * 4 + wave;               // 0..7
    int row = (cb << 3) + (lane >> 3);     // 0..63
    gBoff[it] = ((size_t)(s * OPAD + (nt << 6) + row)) * KDIM + srck;
    lBoff[it] = (unsigned)((cb << 9) + (lane << 3));
  }

  int frow = lane & 15, fk = lane >> 4;
  int axor = frow & 7;

#define STAGE(buf, k0off) do { \
    _Pragma("unroll") \
    for (int it = 0; it < 4; it++) \
      gload16(xs + gAoff[it] + (k0off), (void*)(&lA[buf][lAoff[it]])); \
    _Pragma("unroll") \
    for (int it = 0; it < 2; it++) \
      gload16(Wt + gBoff[it] + (k0off), (void*)(&lB[buf][lBoff[it]])); \
  } while (0)

#define COMPUTE(buf) do { \
    _Pragma("unroll") \
    for (int ks = 0; ks < 2; ks++){ \
      short8v a[4], b[2]; \
      _Pragma("unroll") \
      for (int mi = 0; mi < 4; mi++){ \
        int row = wm + (mi << 4) + frow; \
        int j = (ks << 2) + fk; \
        a[mi] = *(const short8v*)&lA[buf][(row << 6) + ((j ^ axor) << 3)]; \
      } \
      _Pragma("unroll") \
      for (int ni = 0; ni < 2; ni++){ \
        int row = wn + (ni << 4) + frow; \
        int j = (ks << 2) + fk; \
        b[ni] = *(const short8v*)&lB[buf][(row << 6) + ((j ^ axor) << 3)]; \
      } \
      _Pragma("unroll") \
      for (int mi = 0; mi < 4; mi++) \
        _Pragma("unroll") \
        for (int ni = 0; ni < 2; ni++) \
          acc[mi][ni] = __builtin_amdgcn_mfma_f32_16x16x32_bf16(a[mi], b[ni], acc[mi][ni], 0, 0, 0); \
    } \
  } while (0)

  // 2-phase double-buffered pipeline: one barrier per K-step
  STAGE(0, 0);
  __syncthreads();                         // vmcnt(0) drain -> buf0 ready
  int cur = 0;
  for (int k0 = 0; k0 < KDIM - BK; k0 += BK){
    STAGE(cur ^ 1, k0 + BK);               // issue next tile's async loads
    COMPUTE(cur);                          // ds_read + MFMA (compiler lgkmcnt)
    __syncthreads();                       // drains stage; all waves done reading
    cur ^= 1;
  }
  COMPUTE(cur);                            // last tile, no barrier needed

  // epilogue: C/D layout col=lane&15, row=(lane>>4)*4+reg
  float bvn[2]; int ocol[2];
  #pragma unroll
  for (int ni = 0; ni < 2; ni++){
    int o = (nt << 6) + wn + (ni << 4) + frow;
    ocol[ni] = o;
    bvn[ni] = (o < ODIM) ? bias[s * ODIM + o] : 0.f;
  }
  #pragma unroll
  for (int mi = 0; mi < 4; mi++){
    int rbase = wm + (mi << 4) + (fk << 2);
    #pragma unroll
    for (int jj = 0; jj < 4; jj++){
      int orow = permL[rbase + jj];
      if (orow >= 0){
        #pragma unroll
        for (int ni = 0; ni < 2; ni++){
          if (ocol[ni] < ODIM)
            out[(size_t)orow * ODIM + ocol[ni]] = acc[mi][ni][jj] + bvn[ni];
        }
      }
    }
  }
#undef STAGE
#undef COMPUTE
}

// ---------------- fallback: naive fp32 (only if ws too small) ----------------
__global__ __launch_bounds__(256) void naive_kernel(const float* __restrict__ x,
                                                    const int* __restrict__ sid,
                                                    const float* __restrict__ W,
                                                    const float* __restrict__ bias,
                                                    float* __restrict__ out){
  __shared__ float xr[KDIM];
  int row = blockIdx.x;
  int s = sid[row];
  for (int i = threadIdx.x; i < KDIM; i += 256) xr[i] = x[(size_t)row * KDIM + i];
  __syncthreads();
  int o = blockIdx.y * 256 + threadIdx.x;
  if (o >= ODIM) return;
  const float* w = W + (size_t)s * KDIM * ODIM + o;
  float acc = bias[s * ODIM + o];
  for (int k = 0; k < KDIM; k++) acc = fmaf(xr[k], w[(size_t)k * ODIM], acc);
  out[(size_t)row * ODIM + o] = acc;
}

extern "C" void kernel_launch(void* const* d_in, const int* in_sizes, int n_in,
                              void* d_out, int out_size, void* d_ws, size_t ws_size,
                              hipStream_t stream) {
  const float* x    = (const float*)d_in[0];
  const int*   sid  = (const int*)d_in[1];
  const float* W    = (const float*)d_in[2];
  const float* bias = (const float*)d_in[3];
  float* out = (float*)d_out;

  const size_t XS_BYTES = (size_t)NROWS * KDIM * 2;
  const size_t WT_BYTES = (size_t)NSUB * OPAD * KDIM * 2;
  const size_t need = 64 + (size_t)NROWS * 4 + XS_BYTES + WT_BYTES;

  if (ws_size < need){
    naive_kernel<<<dim3(NROWS, 4), 256, 0, stream>>>(x, sid, W, bias, out);
    return;
  }

  char* w = (char*)d_ws;
  int* counts  = (int*)w;                      // 8 ints
  int* offsets = counts + 8;                   // 8 ints
  int* perm    = (int*)(w + 64);               // 8192 ints
  unsigned short* xs = (unsigned short*)(w + 64 + (size_t)NROWS * 4);
  unsigned short* Wt = xs + (size_t)NROWS * KDIM;

  build_perm    <<<NSUB, 256, 0, stream>>>(sid, counts, offsets, perm);
  gather_cvt    <<<NROWS, 256, 0, stream>>>(x, perm, xs);
  transpose_cvt <<<dim3(16, 32, NSUB), 256, 0, stream>>>(W, Wt);
  gemm_bf16     <<<dim3(16, 64, NSUB), 256, 0, stream>>>(xs, Wt, counts, offsets, perm, bias, out);
}